// Round 9
// baseline (199.078 us; speedup 1.0000x reference)
//
#include <hip/hip_runtime.h>
#include <hip/hip_bf16.h>
#include <math.h>

#define VOCAB 50257
#define EMB   1024
#define HID   1024
#define BATCH 64
#define SEQ   512
#define LOGITS_LD 50304
#define SCH   16                  // s-rows per attention chunk
#define NCHUNK (SEQ / SCH)        // 32
#define NSLAB 786                 // 64-vocab-row slabs

typedef __attribute__((ext_vector_type(8))) short bf16x8;
typedef __attribute__((ext_vector_type(4))) float f32x4;

typedef const __attribute__((address_space(1))) unsigned int gu32_t;
typedef __attribute__((address_space(3))) unsigned int lu32_t;

__device__ inline short f2bf(float x) {
    __hip_bfloat16 h = __float2bfloat16(x);
    return *reinterpret_cast<short*>(&h);
}

__device__ inline bf16x8 cvt8(const float4& a, const float4& b) {
    bf16x8 r;
    r[0] = f2bf(a.x); r[1] = f2bf(a.y); r[2] = f2bf(a.z); r[3] = f2bf(a.w);
    r[4] = f2bf(b.x); r[5] = f2bf(b.y); r[6] = f2bf(b.z); r[7] = f2bf(b.w);
    return r;
}

// ---------------------------------------------------------------------------
// Direct-stream MFMA GEMM for the small GEMMs (unchanged).
// ---------------------------------------------------------------------------
struct Prob {
    const void*  A;
    const int*   gidx;
    const float* W;
    const float* bias;
    float*       C;
    int N, K, ldc;
};

template <int KSLEN, int ADD_BIAS, int A_BF16>
__global__ __launch_bounds__(128, 2) void gemm_k(Prob p0, Prob p1, Prob p2)
{
    Prob P = (blockIdx.y == 0) ? p0 : ((blockIdx.y == 1) ? p1 : p2);

    const int lane = threadIdx.x & 63;
    const int wv   = threadIdx.x >> 6;
    const int rowi = lane & 15;
    const int kgi  = lane >> 4;
    const int col  = blockIdx.x * 32 + wv * 16 + rowi;
    const int wcol = min(col, P.N - 1);
    const int kbase = blockIdx.z * KSLEN + kgi * 8;

    const float* wp = P.W + (size_t)wcol * P.K + kbase;

    const float*  af[4];
    const ushort* ah[4];
#pragma unroll
    for (int mt = 0; mt < 4; ++mt) {
        int r  = rowi + mt * 16;
        int ar = P.gidx ? P.gidx[r] : r;
        af[mt] = (const float*) P.A + (size_t)ar * P.K + kbase;
        ah[mt] = (const ushort*)P.A + (size_t)ar * P.K + kbase;
    }

    f32x4 acc[4] = {};

    float4 wa0, wb0, wa1, wb1;
    bf16x8 h0b[4], h1b[4];
    float4 f0a[4], f0b[4], f1a[4], f1b[4];

    wa0 = *(const float4*)(wp);
    wb0 = *(const float4*)(wp + 4);
#pragma unroll
    for (int mt = 0; mt < 4; ++mt) {
        if (A_BF16) h0b[mt] = *(const bf16x8*)(ah[mt]);
        else { f0a[mt] = *(const float4*)(af[mt]); f0b[mt] = *(const float4*)(af[mt] + 4); }
    }
    wa1 = *(const float4*)(wp + 32);
    wb1 = *(const float4*)(wp + 36);
#pragma unroll
    for (int mt = 0; mt < 4; ++mt) {
        if (A_BF16) h1b[mt] = *(const bf16x8*)(ah[mt] + 32);
        else { f1a[mt] = *(const float4*)(af[mt] + 32); f1b[mt] = *(const float4*)(af[mt] + 36); }
    }

#pragma unroll
    for (int ks = 0; ks < KSLEN; ks += 64) {
        {
            float4 nwa = {}, nwb = {};
            bf16x8 nh[4] = {};
            float4 nfa[4] = {}, nfb[4] = {};
            if (ks + 64 < KSLEN) {
                nwa = *(const float4*)(wp + ks + 64);
                nwb = *(const float4*)(wp + ks + 68);
#pragma unroll
                for (int mt = 0; mt < 4; ++mt) {
                    if (A_BF16) nh[mt] = *(const bf16x8*)(ah[mt] + ks + 64);
                    else { nfa[mt] = *(const float4*)(af[mt] + ks + 64);
                           nfb[mt] = *(const float4*)(af[mt] + ks + 68); }
                }
            }
            bf16x8 b = cvt8(wa0, wb0);
#pragma unroll
            for (int mt = 0; mt < 4; ++mt) {
                bf16x8 a;
                if (A_BF16) a = h0b[mt]; else a = cvt8(f0a[mt], f0b[mt]);
                acc[mt] = __builtin_amdgcn_mfma_f32_16x16x32_bf16(a, b, acc[mt], 0, 0, 0);
            }
            wa0 = nwa; wb0 = nwb;
#pragma unroll
            for (int mt = 0; mt < 4; ++mt) {
                if (A_BF16) h0b[mt] = nh[mt];
                else { f0a[mt] = nfa[mt]; f0b[mt] = nfb[mt]; }
            }
        }
        {
            float4 nwa = {}, nwb = {};
            bf16x8 nh[4] = {};
            float4 nfa[4] = {}, nfb[4] = {};
            if (ks + 96 < KSLEN) {
                nwa = *(const float4*)(wp + ks + 96);
                nwb = *(const float4*)(wp + ks + 100);
#pragma unroll
                for (int mt = 0; mt < 4; ++mt) {
                    if (A_BF16) nh[mt] = *(const bf16x8*)(ah[mt] + ks + 96);
                    else { nfa[mt] = *(const float4*)(af[mt] + ks + 96);
                           nfb[mt] = *(const float4*)(af[mt] + ks + 100); }
                }
            }
            bf16x8 b = cvt8(wa1, wb1);
#pragma unroll
            for (int mt = 0; mt < 4; ++mt) {
                bf16x8 a;
                if (A_BF16) a = h1b[mt]; else a = cvt8(f1a[mt], f1b[mt]);
                acc[mt] = __builtin_amdgcn_mfma_f32_16x16x32_bf16(a, b, acc[mt], 0, 0, 0);
            }
            wa1 = nwa; wb1 = nwb;
#pragma unroll
            for (int mt = 0; mt < 4; ++mt) {
                if (A_BF16) h1b[mt] = nh[mt];
                else { f1a[mt] = nfa[mt]; f1b[mt] = nfb[mt]; }
            }
        }
    }

    if (col < P.N) {
        float bv = ADD_BIAS ? P.bias[col] : 0.0f;
        float* C = P.C + (size_t)blockIdx.z * 64 * P.ldc;
#pragma unroll
        for (int mt = 0; mt < 4; ++mt)
#pragma unroll
            for (int r = 0; r < 4; ++r) {
                int row = mt * 16 + kgi * 4 + r;
                C[(size_t)row * P.ldc + col] = acc[mt][r] + bv;
            }
    }
}

// ---------------------------------------------------------------------------
// Persistent logits GEMM, T3+T4 structure:
//   co (64x1024 bf16) LDS-resident (128 KB, swizzled source - verified r8)
//   W staged via global_load_lds into 3x8KB ring; counted vmcnt (never 0 in
//   steady state), raw s_barrier; 16 KB in flight per CU sustained.
//   Fused per-slab softmax stats in epilogue.
// ---------------------------------------------------------------------------
__global__ __launch_bounds__(256) void logits_pers_k(
    const ushort* __restrict__ co_bf, const float* __restrict__ W,
    const float* __restrict__ bias, float* __restrict__ logits,
    float* __restrict__ pmax, float* __restrict__ psum, int* __restrict__ ctr)
{
    __shared__ ushort co_s[64 * 1024];        // 128 KB
    __shared__ float  w_s[3][2048];           // 3 x 8 KB ring
    __shared__ float  smax[4][64], ssum[4][64];
    __shared__ int    slab_sh;

    const int tid  = threadIdx.x;
    const int lane = tid & 63;
    const int wv   = tid >> 6;
    const int rowi = lane & 15;
    const int kgi  = lane >> 4;

    // ---- stage co once (swizzled source, linear dest) ----
#pragma unroll
    for (int rnd = 0; rnd < 32; ++rnd) {
        int o     = rnd * 4096 + tid * 16;
        int row   = o >> 11;
        int inner = o & 2047;
        int src   = (row << 11) + (inner ^ ((row & 7) << 4));
        __builtin_amdgcn_global_load_lds(
            (gu32_t*)((const char*)co_bf + src),
            (lu32_t*)(((char*)co_s) + rnd * 4096 + wv * 1024), 16, 0, 0);
    }
    asm volatile("s_waitcnt vmcnt(0)" ::: "memory");
    __builtin_amdgcn_s_barrier();

    const int rloc = wv * 16 + rowi;
    const int wswz = (rloc & 7) << 4;

    // W stage geometry: chunk = [64 rows][32 floats] = 8 KB, row stride 128 B.
    // instr A covers units 0..255 (rows 0..31), instr B units 256..511.
    const int rowA = tid >> 3;
    const int rowB = 32 + (tid >> 3);
    const int swzA = ((((tid & 7) << 4) ^ ((rowA & 7) << 4)) >> 2);
    const int swzB = ((((tid & 7) << 4) ^ ((rowB & 7) << 4)) >> 2);

    while (true) {
        if (tid == 0) slab_sh = atomicAdd(ctr, 1);
        __syncthreads();
        const int slab = slab_sh;
        __syncthreads();
        if (slab >= NSLAB) break;

        const int r0 = slab * 64;
        const size_t sA = (size_t)min(r0 + rowA, VOCAB - 1) * 1024 + swzA;
        const size_t sB = (size_t)min(r0 + rowB, VOCAB - 1) * 1024 + swzB;

#define STAGE_CHUNK(bufidx, c) do {                                          \
        __builtin_amdgcn_global_load_lds((gu32_t*)(W + sA + (c) * 32),       \
            (lu32_t*)(((char*)w_s) + (bufidx) * 8192 + wv * 1024), 16, 0, 0);\
        __builtin_amdgcn_global_load_lds((gu32_t*)(W + sB + (c) * 32),       \
            (lu32_t*)(((char*)w_s) + (bufidx) * 8192 + 4096 + wv * 1024),    \
            16, 0, 0);                                                       \
    } while (0)

        STAGE_CHUNK(0, 0);
        STAGE_CHUNK(1, 1);
        STAGE_CHUNK(2, 2);

        f32x4 acc[4] = {};

#pragma unroll
        for (int t = 0; t < 32; ++t) {
            if (t < 30)       asm volatile("s_waitcnt vmcnt(4)" ::: "memory");
            else if (t == 30) asm volatile("s_waitcnt vmcnt(2)" ::: "memory");
            else              asm volatile("s_waitcnt vmcnt(0)" ::: "memory");
            __builtin_amdgcn_sched_barrier(0);
            __builtin_amdgcn_s_barrier();
            __builtin_amdgcn_sched_barrier(0);

            const char* wbase = ((const char*)w_s) + (t % 3) * 8192 + rloc * 128;
            float4 wa = *(const float4*)(wbase + ((kgi * 32) ^ wswz));
            float4 wb = *(const float4*)(wbase + ((kgi * 32 + 16) ^ wswz));
            bf16x8 wf = cvt8(wa, wb);
#pragma unroll
            for (int cf = 0; cf < 4; ++cf) {
                int row = cf * 16 + rowi;
                const char* p = ((const char*)co_s) + row * 2048 +
                                ((t * 64 + kgi * 16) ^ ((row & 7) << 4));
                bf16x8 a = *(const bf16x8*)p;
                acc[cf] = __builtin_amdgcn_mfma_f32_16x16x32_bf16(wf, a, acc[cf], 0, 0, 0);
            }

            asm volatile("s_waitcnt lgkmcnt(0)" ::: "memory");
            __builtin_amdgcn_sched_barrier(0);
            __builtin_amdgcn_s_barrier();
            __builtin_amdgcn_sched_barrier(0);
            if (t + 3 < 32) STAGE_CHUNK(t % 3, t + 3);
        }
#undef STAGE_CHUNK

        // ---- epilogue: bias, store logits, per-slab stats ----
        const int nb = r0 + wv * 16 + kgi * 4;
        float vals[4][4];
#pragma unroll
        for (int cf = 0; cf < 4; ++cf) {
            int b = cf * 16 + rowi;
#pragma unroll
            for (int r = 0; r < 4; ++r)
                vals[cf][r] = acc[cf][r] + bias[min(nb + r, VOCAB - 1)];
            float4 o = {vals[cf][0], vals[cf][1], vals[cf][2], vals[cf][3]};
            *(float4*)(logits + (size_t)b * LOGITS_LD + nb) = o;
        }
#pragma unroll
        for (int cf = 0; cf < 4; ++cf) {
            float m = -INFINITY;
#pragma unroll
            for (int r = 0; r < 4; ++r)
                if (nb + r < VOCAB) m = fmaxf(m, vals[cf][r]);
            m = fmaxf(m, __shfl_xor(m, 16));
            m = fmaxf(m, __shfl_xor(m, 32));
            float sm = 0.0f;
#pragma unroll
            for (int r = 0; r < 4; ++r)
                if (nb + r < VOCAB) sm += expf(vals[cf][r] - m);
            sm += __shfl_xor(sm, 16);
            sm += __shfl_xor(sm, 32);
            if (kgi == 0) { smax[wv][cf * 16 + rowi] = m; ssum[wv][cf * 16 + rowi] = sm; }
        }
        __syncthreads();
        if (tid < 64) {
            float m = fmaxf(fmaxf(smax[0][tid], smax[1][tid]),
                            fmaxf(smax[2][tid], smax[3][tid]));
            float t = 0.0f;
#pragma unroll
            for (int w = 0; w < 4; ++w) {
                float sw = ssum[w][tid];
                t += (sw > 0.0f) ? sw * expf(smax[w][tid] - m) : 0.0f;
            }
            pmax[(size_t)slab * 64 + tid] = m;
            psum[(size_t)slab * 64 + tid] = t;
        }
        __syncthreads();
    }
}

// ---------------------------------------------------------------------------
// Combine per-slab stats -> per-batch global max and 1/sum
// ---------------------------------------------------------------------------
__global__ __launch_bounds__(256) void vfinal_k(
    const float* __restrict__ pmax, const float* __restrict__ psum,
    float* __restrict__ gm, float* __restrict__ ginv)
{
    const int b = blockIdx.x;
    __shared__ float red[4];
    float m = -INFINITY;
    for (int s = threadIdx.x; s < NSLAB; s += 256)
        m = fmaxf(m, pmax[(size_t)s * 64 + b]);
    for (int off = 32; off; off >>= 1) m = fmaxf(m, __shfl_xor(m, off));
    int wv = threadIdx.x >> 6, lane = threadIdx.x & 63;
    if (lane == 0) red[wv] = m;
    __syncthreads();
    m = fmaxf(fmaxf(red[0], red[1]), fmaxf(red[2], red[3]));
    float t = 0.0f;
    for (int s = threadIdx.x; s < NSLAB; s += 256)
        t += psum[(size_t)s * 64 + b] * expf(pmax[(size_t)s * 64 + b] - m);
    for (int off = 32; off; off >>= 1) t += __shfl_xor(t, off);
    __syncthreads();
    if (lane == 0) red[wv] = t;
    __syncthreads();
    if (threadIdx.x == 0) { gm[b] = m; ginv[b] = 1.0f / (red[0] + red[1] + red[2] + red[3]); }
}

// ---------------------------------------------------------------------------
// GRU gate fusion over split-K partials (NZI for gi, NZH for gh).
// ---------------------------------------------------------------------------
template <int NZI, int NZH>
__global__ __launch_bounds__(256) void gru_gate_k(
    const float* __restrict__ pgi, const float* __restrict__ pgh,
    const float* __restrict__ b_ih, const float* __restrict__ b_hh,
    const float* __restrict__ hprev, float* __restrict__ out_hidden,
    float* __restrict__ h_out, float* __restrict__ ci)
{
    int i = blockIdx.x * 256 + threadIdx.x;
    int b = i >> 10, j = i & 1023;
    size_t base = (size_t)b * 3072 + j;
    float ir = b_ih[j], iz = b_ih[j + 1024], in_ = b_ih[j + 2048];
    float hr = b_hh[j], hz = b_hh[j + 1024], hn  = b_hh[j + 2048];
#pragma unroll
    for (int z = 0; z < NZI; ++z) {
        size_t o = (size_t)z * 64 * 3072 + base;
        ir += pgi[o]; iz += pgi[o + 1024]; in_ += pgi[o + 2048];
    }
#pragma unroll
    for (int z = 0; z < NZH; ++z) {
        size_t o = (size_t)z * 64 * 3072 + base;
        hr += pgh[o]; hz += pgh[o + 1024]; hn  += pgh[o + 2048];
    }
    float r = 1.0f / (1.0f + expf(-(ir + hr)));
    float z = 1.0f / (1.0f + expf(-(iz + hz)));
    float n = tanhf(in_ + r * hn);
    float v = (1.0f - z) * n + z * hprev[i];
    out_hidden[i] = v;
    if (h_out) h_out[i] = v;
    if (ci)    ci[(size_t)b * 2048 + j] = v;
}

// ---------------------------------------------------------------------------
// Single-pass flash attention chunk: per (chunk of 16 s, b).
// ---------------------------------------------------------------------------
__global__ __launch_bounds__(256) void attn_fused_k(
    const float* __restrict__ h1, const float* __restrict__ enc,
    float* __restrict__ pctx, float* __restrict__ pm, float* __restrict__ ps)
{
    const int b = blockIdx.y, ck = blockIdx.x;
    __shared__ float hs[HID];
    __shared__ float es[SCH][HID];
    __shared__ float sc[SCH];
    const int tid = threadIdx.x, wv = tid >> 6, lane = tid & 63;

    ((float4*)hs)[tid] = ((const float4*)(h1 + (size_t)b * HID))[tid];
    const float* ebase = enc + ((size_t)(ck * SCH) * BATCH + b) * HID;
#pragma unroll
    for (int i = 0; i < SCH; ++i) {
        int idx = tid + i * 256;
        int r = idx >> 8, c = idx & 255;
        ((float4*)es[r])[c] = ((const float4*)(ebase + (size_t)r * BATCH * HID))[c];
    }
    __syncthreads();

#pragma unroll
    for (int i = 0; i < 4; ++i) {
        int r = wv * 4 + i;
        float acc = 0.0f;
#pragma unroll
        for (int seg = 0; seg < 4; ++seg) {
            float4 ev = ((const float4*)es[r])[lane + seg * 64];
            float4 hv = ((const float4*)hs)[lane + seg * 64];
            acc += ev.x * hv.x + ev.y * hv.y + ev.z * hv.z + ev.w * hv.w;
        }
        for (int off = 32; off; off >>= 1) acc += __shfl_down(acc, off);
        if (lane == 0) sc[r] = acc;
    }
    __syncthreads();

    float m = sc[0];
#pragma unroll
    for (int s = 1; s < SCH; ++s) m = fmaxf(m, sc[s]);
    float p[SCH];
    float sum = 0.0f;
#pragma unroll
    for (int s = 0; s < SCH; ++s) { p[s] = expf(sc[s] - m); sum += p[s]; }

    float4 cacc = {0.0f, 0.0f, 0.0f, 0.0f};
#pragma unroll
    for (int s = 0; s < SCH; ++s) {
        float4 ev = ((const float4*)es[s])[tid];
        cacc.x += p[s] * ev.x; cacc.y += p[s] * ev.y;
        cacc.z += p[s] * ev.z; cacc.w += p[s] * ev.w;
    }
    ((float4*)(pctx + ((size_t)ck * BATCH + b) * HID))[tid] = cacc;
    if (tid == 0) { pm[b * NCHUNK + ck] = m; ps[b * NCHUNK + ck] = sum; }
}

// ---------------------------------------------------------------------------
// Attention combine: merge 32 chunk partials -> ci[:,1024:] (fp32)
// ---------------------------------------------------------------------------
__global__ __launch_bounds__(256) void attn_comb_k(
    const float* __restrict__ pctx, const float* __restrict__ pm,
    const float* __restrict__ ps, float* __restrict__ ci)
{
    const int b = blockIdx.x, tid = threadIdx.x;
    float m = -INFINITY;
#pragma unroll
    for (int c = 0; c < NCHUNK; ++c) m = fmaxf(m, pm[b * NCHUNK + c]);
    float w[NCHUNK]; float tot = 0.0f;
#pragma unroll
    for (int c = 0; c < NCHUNK; ++c) {
        w[c] = expf(pm[b * NCHUNK + c] - m);
        tot += ps[b * NCHUNK + c] * w[c];
    }
    float inv = 1.0f / tot;
    float4 acc = {0.0f, 0.0f, 0.0f, 0.0f};
#pragma unroll
    for (int c = 0; c < NCHUNK; ++c) {
        float4 v = ((const float4*)(pctx + ((size_t)c * BATCH + b) * HID))[tid];
        acc.x += w[c] * v.x; acc.y += w[c] * v.y;
        acc.z += w[c] * v.z; acc.w += w[c] * v.w;
    }
    float4 o = {acc.x * inv, acc.y * inv, acc.z * inv, acc.w * inv};
    ((float4*)(ci + (size_t)b * 2048 + 1024))[tid] = o;
}

// ---------------------------------------------------------------------------
// Concat combine: co_bf = bf16(tanh(sum of 8 partials + bias)); init counter.
// ---------------------------------------------------------------------------
__global__ __launch_bounds__(256) void concat_comb_k(
    const float* __restrict__ pco, const float* __restrict__ bias,
    ushort* __restrict__ co_bf, int* __restrict__ ctr)
{
    if (blockIdx.x == 0 && threadIdx.x == 0) *ctr = 0;
    int i = blockIdx.x * 256 + threadIdx.x;
    int j = i & 1023;
    float v = bias[j];
#pragma unroll
    for (int z = 0; z < 8; ++z) v += pco[(size_t)z * 65536 + i];
    co_bf[i] = (ushort)f2bf(tanhf(v));
}

// ---------------------------------------------------------------------------
// Softmax normalize over VOCAB using precomputed gm/ginv
// ---------------------------------------------------------------------------
__global__ __launch_bounds__(256) void softmax_v_k(
    const float* __restrict__ logits, const float* __restrict__ gm,
    const float* __restrict__ ginv, float* __restrict__ out)
{
    int b = blockIdx.y;
    float m = gm[b], inv = ginv[b];
    int v = blockIdx.x * 1024 + threadIdx.x * 4;
    if (v + 3 < VOCAB) {
        float4 lv = *reinterpret_cast<const float4*>(logits + (size_t)b * LOGITS_LD + v);
        float4 o;
        o.x = expf(lv.x - m) * inv; o.y = expf(lv.y - m) * inv;
        o.z = expf(lv.z - m) * inv; o.w = expf(lv.w - m) * inv;
        *reinterpret_cast<float4*>(out + (size_t)b * VOCAB + v) = o;
    } else {
        for (int k = 0; k < 4 && v + k < VOCAB; ++k)
            out[(size_t)b * VOCAB + v + k] = expf(logits[(size_t)b * LOGITS_LD + v + k] - m) * inv;
    }
}

// ---------------------------------------------------------------------------
extern "C" void kernel_launch(void* const* d_in, const int* in_sizes, int n_in,
                              void* d_out, int out_size, void* d_ws, size_t ws_size,
                              hipStream_t stream)
{
    const int*   input_step  = (const int*)  d_in[0];
    const float* last_hidden = (const float*)d_in[1];
    const float* enc         = (const float*)d_in[2];
    const float* emb         = (const float*)d_in[3];
    const float* w_ih0       = (const float*)d_in[4];
    const float* w_hh0       = (const float*)d_in[5];
    const float* b_ih0       = (const float*)d_in[6];
    const float* b_hh0       = (const float*)d_in[7];
    const float* w_ih1       = (const float*)d_in[8];
    const float* w_hh1       = (const float*)d_in[9];
    const float* b_ih1       = (const float*)d_in[10];
    const float* b_hh1       = (const float*)d_in[11];
    const float* concat_w    = (const float*)d_in[12];
    const float* concat_b    = (const float*)d_in[13];
    const float* out_w       = (const float*)d_in[14];
    const float* out_b       = (const float*)d_in[15];

    float* out = (float*)d_out;
    float* out_probs  = out;
    float* out_hidden = out + (size_t)BATCH * VOCAB;

    float* ws   = (float*)d_ws;
    float* big  = ws;                               // aliased region
    float* pgi0 = big;
    float* pgh0 = big + 786432;
    float* pgh1 = big + 1572864;
    float* pgi1 = big;                              // alias
    float* pctx = big;                              // alias
    float* pco  = big;                              // alias
    float* logits = ws + 2359296;                   // 64*LOGITS_LD = 3219456
    float* ci   = logits + (size_t)64 * LOGITS_LD;  // 131072
    float* h0   = ci + 131072;                      // 65536
    float* pm   = h0 + 65536;                       // 2048
    float* ps   = pm + 2048;                        // 2048
    float* pmax = ps + 2048;                        // NSLAB*64 = 50304
    float* psum = pmax + 50304;                     // 50304
    float* gm   = psum + 50304;                     // 64
    float* ginv = gm + 64;                          // 64
    int*   ctr  = (int*)(ginv + 64);                // 16 floats reserved
    ushort* co_bf = (ushort*)(ginv + 64 + 16);      // 65536 ushorts

    Prob P0 = { emb,         input_step, w_ih0, nullptr, pgi0, 3 * HID, EMB, 3 * HID };
    Prob P1 = { last_hidden, nullptr,    w_hh0, nullptr, pgh0, 3 * HID, HID, 3 * HID };
    Prob P2 = { last_hidden + 64 * HID, nullptr, w_hh1, nullptr, pgh1, 3 * HID, HID, 3 * HID };

    // 1. triple GEMM: gi0 (emb-gather), gh0, gh1 — independent. split-K 4.
    gemm_k<256, 0, 0><<<dim3(96, 3, 4), 128, 0, stream>>>(P0, P1, P2);

    // 2. gate layer 0 -> h0 (fp32), out_hidden[0]
    gru_gate_k<4, 4><<<256, 256, 0, stream>>>(pgi0, pgh0, b_ih0, b_hh0, last_hidden,
                                              out_hidden, h0, nullptr);

    // 3. gi1 = h0 @ w_ih1, split-K 8
    Prob PB = { h0, nullptr, w_ih1, nullptr, pgi1, 3 * HID, HID, 3 * HID };
    gemm_k<128, 0, 0><<<dim3(96, 1, 8), 128, 0, stream>>>(PB, PB, PB);

    // 4. gate layer 1 -> out_hidden[1], ci[:, :1024]
    gru_gate_k<8, 4><<<256, 256, 0, stream>>>(pgi1, pgh1, b_ih1, b_hh1,
                                              last_hidden + 64 * HID,
                                              out_hidden + 64 * HID, nullptr, ci);

    // 5. attention: single-pass flash over 32 chunks of 16, then combine
    attn_fused_k<<<dim3(NCHUNK, BATCH), 256, 0, stream>>>(
        out_hidden + 64 * HID, enc, pctx, pm, ps);
    attn_comb_k<<<BATCH, 256, 0, stream>>>(pctx, pm, ps, ci);

    // 6. concat projection: split-K 8 + tanh combine -> co_bf (bf16) + ctr init
    Prob PC = { ci, nullptr, concat_w, nullptr, pco, HID, 2 * HID, HID };
    gemm_k<256, 0, 0><<<dim3(32, 1, 8), 128, 0, stream>>>(PC, PC, PC);
    concat_comb_k<<<256, 256, 0, stream>>>(pco, concat_b, co_bf, ctr);

    // 7. persistent logits GEMM (counted-vmcnt pipeline) + fused slab stats
    logits_pers_k<<<256, 256, 0, stream>>>(co_bf, out_w, out_b, logits, pmax, psum, ctr);

    // 8. stats combine + softmax normalize
    vfinal_k<<<BATCH, 256, 0, stream>>>(pmax, psum, gm, ginv);
    softmax_v_k<<<dim3((VOCAB + 1023) / 1024, BATCH), 256, 0, stream>>>(
        logits, gm, ginv, out_probs);
}

// Round 10
// 172.219 us; speedup vs baseline: 1.1560x; 1.1560x over previous
//
#include <hip/hip_runtime.h>
#include <hip/hip_bf16.h>
#include <math.h>

#define VOCAB 50257
#define EMB   1024
#define HID   1024
#define BATCH 64
#define SEQ   512
#define LOGITS_LD 50304
#define SCH   16                  // s-rows per attention chunk
#define NCHUNK (SEQ / SCH)        // 32
#define NSLAB 786                 // 64-vocab-row slabs

typedef __attribute__((ext_vector_type(8))) short bf16x8;
typedef __attribute__((ext_vector_type(4))) float f32x4;

__device__ inline short f2bf(float x) {
    __hip_bfloat16 h = __float2bfloat16(x);
    return *reinterpret_cast<short*>(&h);
}

__device__ inline bf16x8 cvt8(const float4& a, const float4& b) {
    bf16x8 r;
    r[0] = f2bf(a.x); r[1] = f2bf(a.y); r[2] = f2bf(a.z); r[3] = f2bf(a.w);
    r[4] = f2bf(b.x); r[5] = f2bf(b.y); r[6] = f2bf(b.z); r[7] = f2bf(b.w);
    return r;
}

// ---------------------------------------------------------------------------
// Direct-stream MFMA GEMM for the small GEMMs (unchanged).
// ---------------------------------------------------------------------------
struct Prob {
    const void*  A;
    const int*   gidx;
    const float* W;
    const float* bias;
    float*       C;
    int N, K, ldc;
};

template <int KSLEN, int ADD_BIAS, int A_BF16>
__global__ __launch_bounds__(128, 2) void gemm_k(Prob p0, Prob p1, Prob p2)
{
    Prob P = (blockIdx.y == 0) ? p0 : ((blockIdx.y == 1) ? p1 : p2);

    const int lane = threadIdx.x & 63;
    const int wv   = threadIdx.x >> 6;
    const int rowi = lane & 15;
    const int kgi  = lane >> 4;
    const int col  = blockIdx.x * 32 + wv * 16 + rowi;
    const int wcol = min(col, P.N - 1);
    const int kbase = blockIdx.z * KSLEN + kgi * 8;

    const float* wp = P.W + (size_t)wcol * P.K + kbase;

    const float*  af[4];
    const ushort* ah[4];
#pragma unroll
    for (int mt = 0; mt < 4; ++mt) {
        int r  = rowi + mt * 16;
        int ar = P.gidx ? P.gidx[r] : r;
        af[mt] = (const float*) P.A + (size_t)ar * P.K + kbase;
        ah[mt] = (const ushort*)P.A + (size_t)ar * P.K + kbase;
    }

    f32x4 acc[4] = {};

    float4 wa0, wb0, wa1, wb1;
    bf16x8 h0b[4], h1b[4];
    float4 f0a[4], f0b[4], f1a[4], f1b[4];

    wa0 = *(const float4*)(wp);
    wb0 = *(const float4*)(wp + 4);
#pragma unroll
    for (int mt = 0; mt < 4; ++mt) {
        if (A_BF16) h0b[mt] = *(const bf16x8*)(ah[mt]);
        else { f0a[mt] = *(const float4*)(af[mt]); f0b[mt] = *(const float4*)(af[mt] + 4); }
    }
    wa1 = *(const float4*)(wp + 32);
    wb1 = *(const float4*)(wp + 36);
#pragma unroll
    for (int mt = 0; mt < 4; ++mt) {
        if (A_BF16) h1b[mt] = *(const bf16x8*)(ah[mt] + 32);
        else { f1a[mt] = *(const float4*)(af[mt] + 32); f1b[mt] = *(const float4*)(af[mt] + 36); }
    }

#pragma unroll
    for (int ks = 0; ks < KSLEN; ks += 64) {
        {
            float4 nwa = {}, nwb = {};
            bf16x8 nh[4] = {};
            float4 nfa[4] = {}, nfb[4] = {};
            if (ks + 64 < KSLEN) {
                nwa = *(const float4*)(wp + ks + 64);
                nwb = *(const float4*)(wp + ks + 68);
#pragma unroll
                for (int mt = 0; mt < 4; ++mt) {
                    if (A_BF16) nh[mt] = *(const bf16x8*)(ah[mt] + ks + 64);
                    else { nfa[mt] = *(const float4*)(af[mt] + ks + 64);
                           nfb[mt] = *(const float4*)(af[mt] + ks + 68); }
                }
            }
            bf16x8 b = cvt8(wa0, wb0);
#pragma unroll
            for (int mt = 0; mt < 4; ++mt) {
                bf16x8 a;
                if (A_BF16) a = h0b[mt]; else a = cvt8(f0a[mt], f0b[mt]);
                acc[mt] = __builtin_amdgcn_mfma_f32_16x16x32_bf16(a, b, acc[mt], 0, 0, 0);
            }
            wa0 = nwa; wb0 = nwb;
#pragma unroll
            for (int mt = 0; mt < 4; ++mt) {
                if (A_BF16) h0b[mt] = nh[mt];
                else { f0a[mt] = nfa[mt]; f0b[mt] = nfb[mt]; }
            }
        }
        {
            float4 nwa = {}, nwb = {};
            bf16x8 nh[4] = {};
            float4 nfa[4] = {}, nfb[4] = {};
            if (ks + 96 < KSLEN) {
                nwa = *(const float4*)(wp + ks + 96);
                nwb = *(const float4*)(wp + ks + 100);
#pragma unroll
                for (int mt = 0; mt < 4; ++mt) {
                    if (A_BF16) nh[mt] = *(const bf16x8*)(ah[mt] + ks + 96);
                    else { nfa[mt] = *(const float4*)(af[mt] + ks + 96);
                           nfb[mt] = *(const float4*)(af[mt] + ks + 100); }
                }
            }
            bf16x8 b = cvt8(wa1, wb1);
#pragma unroll
            for (int mt = 0; mt < 4; ++mt) {
                bf16x8 a;
                if (A_BF16) a = h1b[mt]; else a = cvt8(f1a[mt], f1b[mt]);
                acc[mt] = __builtin_amdgcn_mfma_f32_16x16x32_bf16(a, b, acc[mt], 0, 0, 0);
            }
            wa1 = nwa; wb1 = nwb;
#pragma unroll
            for (int mt = 0; mt < 4; ++mt) {
                if (A_BF16) h1b[mt] = nh[mt];
                else { f1a[mt] = nfa[mt]; f1b[mt] = nfb[mt]; }
            }
        }
    }

    if (col < P.N) {
        float bv = ADD_BIAS ? P.bias[col] : 0.0f;
        float* C = P.C + (size_t)blockIdx.z * 64 * P.ldc;
#pragma unroll
        for (int mt = 0; mt < 4; ++mt)
#pragma unroll
            for (int r = 0; r < 4; ++r) {
                int row = mt * 16 + kgi * 4 + r;
                C[(size_t)row * P.ldc + col] = acc[mt][r] + bv;
            }
    }
}

// ---------------------------------------------------------------------------
// Panel-contiguous persistent logits GEMM + fused per-slab softmax stats.
// Slab = 64 vocab rows (256 KB contiguous of W). Panel = 16 rows (64 KB).
// Per panel: whole block reads the 64 KB SEQUENTIALLY into registers (16
// float4/thread, issued one panel ahead - T14), cvt to bf16, ds_write into a
// double-buffered 32 KB LDS panel (swizzled on write AND read). co lives in
// registers (32 x bf16x8 per lane). Raw s_barrier + lgkmcnt only (no vmcnt
// drain) so next panel's loads stay in flight across the barrier.
// ---------------------------------------------------------------------------
__device__ __forceinline__ void issue_panel(const float* __restrict__ W, int r0,
                                            int p, int tid, float4 (&stg)[16])
{
#pragma unroll
    for (int i = 0; i < 16; ++i) {
        int grow = min(r0 + p * 16 + i, VOCAB - 1);
        stg[i] = *(const float4*)(W + (size_t)grow * 1024 + tid * 4);
    }
}

__device__ __forceinline__ void write_panel(ushort* buf, int tid,
                                            const float4 (&stg)[16])
{
#pragma unroll
    for (int i = 0; i < 16; ++i) {
        unsigned lo = (unsigned)(unsigned short)f2bf(stg[i].x) |
                      ((unsigned)(unsigned short)f2bf(stg[i].y) << 16);
        unsigned hi = (unsigned)(unsigned short)f2bf(stg[i].z) |
                      ((unsigned)(unsigned short)f2bf(stg[i].w) << 16);
        uint2 u = {lo, hi};
        *(uint2*)((char*)buf + i * 2048 + ((tid * 8) ^ ((i & 7) << 4))) = u;
    }
}

__global__ __launch_bounds__(256, 2) void logits_panel_k(
    const ushort* __restrict__ co_bf, const float* __restrict__ W,
    const float* __restrict__ bias, float* __restrict__ logits,
    float* __restrict__ pmax, float* __restrict__ psum, int* __restrict__ ctr)
{
    __shared__ ushort wp_s[2][16 * 1024];   // 2 x 32 KB bf16 panels
    __shared__ int slab_sh;

    const int tid  = threadIdx.x;
    const int lane = tid & 63;
    const int wv   = tid >> 6;
    const int rowi = lane & 15;
    const int kgi  = lane >> 4;
    const int wswz = (rowi & 7) << 4;

    // co -> registers: batch b = wv*16 + rowi, full K (32 x bf16x8)
    bf16x8 cob[32];
    {
        const ushort* cp = co_bf + (size_t)(wv * 16 + rowi) * 1024 + kgi * 8;
#pragma unroll
        for (int s = 0; s < 32; ++s)
            cob[s] = *(const bf16x8*)(cp + s * 32);
    }

    while (true) {
        if (tid == 0) slab_sh = atomicAdd(ctr, 1);
        __syncthreads();
        const int slab = slab_sh;
        __syncthreads();
        if (slab >= NSLAB) break;
        const int r0 = slab * 64;

        float4 stg[16];

        // prologue: panel 0 staged, panel 1 issued
        issue_panel(W, r0, 0, tid, stg);
        write_panel(wp_s[0], tid, stg);
        issue_panel(W, r0, 1, tid, stg);
        asm volatile("s_waitcnt lgkmcnt(0)" ::: "memory");
        __builtin_amdgcn_s_barrier();

        float m_run = -INFINITY, s_run = 0.0f;

#pragma unroll
        for (int p = 0; p < 4; ++p) {
            // ---- compute panel p ----
            f32x4 acc = {};
#pragma unroll
            for (int ks = 0; ks < 32; ++ks) {
                bf16x8 wf = *(const bf16x8*)((const char*)wp_s[p & 1] +
                            rowi * 2048 + ((ks * 64 + kgi * 16) ^ wswz));
                acc = __builtin_amdgcn_mfma_f32_16x16x32_bf16(wf, cob[ks], acc, 0, 0, 0);
            }

            // ---- epilogue panel p: bias, store, stats ----
            const int vb = r0 + p * 16 + kgi * 4;        // vocab base (lane)
            const int bq = wv * 16 + rowi;               // batch (lane)
            float vals[4];
            if (vb + 3 < VOCAB) {
                float4 bv = *(const float4*)(bias + vb);
                vals[0] = acc[0] + bv.x; vals[1] = acc[1] + bv.y;
                vals[2] = acc[2] + bv.z; vals[3] = acc[3] + bv.w;
            } else {
#pragma unroll
                for (int r = 0; r < 4; ++r)
                    vals[r] = acc[r] + bias[min(vb + r, VOCAB - 1)];
            }
            float4 o = {vals[0], vals[1], vals[2], vals[3]};
            *(float4*)(logits + (size_t)bq * LOGITS_LD + vb) = o;   // LD padded

            float pmv = -INFINITY;
#pragma unroll
            for (int r = 0; r < 4; ++r)
                if (vb + r < VOCAB) pmv = fmaxf(pmv, vals[r]);
            pmv = fmaxf(pmv, __shfl_xor(pmv, 16));
            pmv = fmaxf(pmv, __shfl_xor(pmv, 32));
            float sp = 0.0f;
#pragma unroll
            for (int r = 0; r < 4; ++r)
                if (vb + r < VOCAB) sp += expf(vals[r] - pmv);
            sp += __shfl_xor(sp, 16);
            sp += __shfl_xor(sp, 32);
            float nm = fmaxf(m_run, pmv);
            s_run = s_run * expf(m_run - nm) +
                    ((pmv == -INFINITY) ? 0.0f : sp * expf(pmv - nm));
            m_run = nm;

            // ---- staging phase: write p+1, issue p+2 ----
            if (p < 3) {
                write_panel(wp_s[(p + 1) & 1], tid, stg);
                if (p < 2) issue_panel(W, r0, p + 2, tid, stg);
                asm volatile("s_waitcnt lgkmcnt(0)" ::: "memory");
                __builtin_amdgcn_s_barrier();
            }
        }

        if (kgi == 0) {
            pmax[(size_t)slab * 64 + wv * 16 + rowi] = m_run;
            psum[(size_t)slab * 64 + wv * 16 + rowi] = s_run;
        }
        __syncthreads();   // all waves done with both LDS panels before reuse
    }
}

// ---------------------------------------------------------------------------
// Combine per-slab stats -> per-batch global max and 1/sum
// ---------------------------------------------------------------------------
__global__ __launch_bounds__(256) void vfinal_k(
    const float* __restrict__ pmax, const float* __restrict__ psum,
    float* __restrict__ gm, float* __restrict__ ginv)
{
    const int b = blockIdx.x;
    __shared__ float red[4];
    float m = -INFINITY;
    for (int s = threadIdx.x; s < NSLAB; s += 256)
        m = fmaxf(m, pmax[(size_t)s * 64 + b]);
    for (int off = 32; off; off >>= 1) m = fmaxf(m, __shfl_xor(m, off));
    int wv = threadIdx.x >> 6, lane = threadIdx.x & 63;
    if (lane == 0) red[wv] = m;
    __syncthreads();
    m = fmaxf(fmaxf(red[0], red[1]), fmaxf(red[2], red[3]));
    float t = 0.0f;
    for (int s = threadIdx.x; s < NSLAB; s += 256)
        t += psum[(size_t)s * 64 + b] * expf(pmax[(size_t)s * 64 + b] - m);
    for (int off = 32; off; off >>= 1) t += __shfl_xor(t, off);
    __syncthreads();
    if (lane == 0) red[wv] = t;
    __syncthreads();
    if (threadIdx.x == 0) { gm[b] = m; ginv[b] = 1.0f / (red[0] + red[1] + red[2] + red[3]); }
}

// ---------------------------------------------------------------------------
// GRU gate fusion over split-K partials (NZI for gi, NZH for gh).
// ---------------------------------------------------------------------------
template <int NZI, int NZH>
__global__ __launch_bounds__(256) void gru_gate_k(
    const float* __restrict__ pgi, const float* __restrict__ pgh,
    const float* __restrict__ b_ih, const float* __restrict__ b_hh,
    const float* __restrict__ hprev, float* __restrict__ out_hidden,
    float* __restrict__ h_out, float* __restrict__ ci)
{
    int i = blockIdx.x * 256 + threadIdx.x;
    int b = i >> 10, j = i & 1023;
    size_t base = (size_t)b * 3072 + j;
    float ir = b_ih[j], iz = b_ih[j + 1024], in_ = b_ih[j + 2048];
    float hr = b_hh[j], hz = b_hh[j + 1024], hn  = b_hh[j + 2048];
#pragma unroll
    for (int z = 0; z < NZI; ++z) {
        size_t o = (size_t)z * 64 * 3072 + base;
        ir += pgi[o]; iz += pgi[o + 1024]; in_ += pgi[o + 2048];
    }
#pragma unroll
    for (int z = 0; z < NZH; ++z) {
        size_t o = (size_t)z * 64 * 3072 + base;
        hr += pgh[o]; hz += pgh[o + 1024]; hn  += pgh[o + 2048];
    }
    float r = 1.0f / (1.0f + expf(-(ir + hr)));
    float z = 1.0f / (1.0f + expf(-(iz + hz)));
    float n = tanhf(in_ + r * hn);
    float v = (1.0f - z) * n + z * hprev[i];
    out_hidden[i] = v;
    if (h_out) h_out[i] = v;
    if (ci)    ci[(size_t)b * 2048 + j] = v;
}

// ---------------------------------------------------------------------------
// Single-pass flash attention chunk: per (chunk of 16 s, b).
// ---------------------------------------------------------------------------
__global__ __launch_bounds__(256) void attn_fused_k(
    const float* __restrict__ h1, const float* __restrict__ enc,
    float* __restrict__ pctx, float* __restrict__ pm, float* __restrict__ ps)
{
    const int b = blockIdx.y, ck = blockIdx.x;
    __shared__ float hs[HID];
    __shared__ float es[SCH][HID];
    __shared__ float sc[SCH];
    const int tid = threadIdx.x, wv = tid >> 6, lane = tid & 63;

    ((float4*)hs)[tid] = ((const float4*)(h1 + (size_t)b * HID))[tid];
    const float* ebase = enc + ((size_t)(ck * SCH) * BATCH + b) * HID;
#pragma unroll
    for (int i = 0; i < SCH; ++i) {
        int idx = tid + i * 256;
        int r = idx >> 8, c = idx & 255;
        ((float4*)es[r])[c] = ((const float4*)(ebase + (size_t)r * BATCH * HID))[c];
    }
    __syncthreads();

#pragma unroll
    for (int i = 0; i < 4; ++i) {
        int r = wv * 4 + i;
        float acc = 0.0f;
#pragma unroll
        for (int seg = 0; seg < 4; ++seg) {
            float4 ev = ((const float4*)es[r])[lane + seg * 64];
            float4 hv = ((const float4*)hs)[lane + seg * 64];
            acc += ev.x * hv.x + ev.y * hv.y + ev.z * hv.z + ev.w * hv.w;
        }
        for (int off = 32; off; off >>= 1) acc += __shfl_down(acc, off);
        if (lane == 0) sc[r] = acc;
    }
    __syncthreads();

    float m = sc[0];
#pragma unroll
    for (int s = 1; s < SCH; ++s) m = fmaxf(m, sc[s]);
    float p[SCH];
    float sum = 0.0f;
#pragma unroll
    for (int s = 0; s < SCH; ++s) { p[s] = expf(sc[s] - m); sum += p[s]; }

    float4 cacc = {0.0f, 0.0f, 0.0f, 0.0f};
#pragma unroll
    for (int s = 0; s < SCH; ++s) {
        float4 ev = ((const float4*)es[s])[tid];
        cacc.x += p[s] * ev.x; cacc.y += p[s] * ev.y;
        cacc.z += p[s] * ev.z; cacc.w += p[s] * ev.w;
    }
    ((float4*)(pctx + ((size_t)ck * BATCH + b) * HID))[tid] = cacc;
    if (tid == 0) { pm[b * NCHUNK + ck] = m; ps[b * NCHUNK + ck] = sum; }
}

// ---------------------------------------------------------------------------
// Attention combine: merge 32 chunk partials -> ci[:,1024:] (fp32)
// ---------------------------------------------------------------------------
__global__ __launch_bounds__(256) void attn_comb_k(
    const float* __restrict__ pctx, const float* __restrict__ pm,
    const float* __restrict__ ps, float* __restrict__ ci)
{
    const int b = blockIdx.x, tid = threadIdx.x;
    float m = -INFINITY;
#pragma unroll
    for (int c = 0; c < NCHUNK; ++c) m = fmaxf(m, pm[b * NCHUNK + c]);
    float w[NCHUNK]; float tot = 0.0f;
#pragma unroll
    for (int c = 0; c < NCHUNK; ++c) {
        w[c] = expf(pm[b * NCHUNK + c] - m);
        tot += ps[b * NCHUNK + c] * w[c];
    }
    float inv = 1.0f / tot;
    float4 acc = {0.0f, 0.0f, 0.0f, 0.0f};
#pragma unroll
    for (int c = 0; c < NCHUNK; ++c) {
        float4 v = ((const float4*)(pctx + ((size_t)c * BATCH + b) * HID))[tid];
        acc.x += w[c] * v.x; acc.y += w[c] * v.y;
        acc.z += w[c] * v.z; acc.w += w[c] * v.w;
    }
    float4 o = {acc.x * inv, acc.y * inv, acc.z * inv, acc.w * inv};
    ((float4*)(ci + (size_t)b * 2048 + 1024))[tid] = o;
}

// ---------------------------------------------------------------------------
// Concat combine: co_bf = bf16(tanh(sum of 8 partials + bias)); init counter.
// ---------------------------------------------------------------------------
__global__ __launch_bounds__(256) void concat_comb_k(
    const float* __restrict__ pco, const float* __restrict__ bias,
    ushort* __restrict__ co_bf, int* __restrict__ ctr)
{
    if (blockIdx.x == 0 && threadIdx.x == 0) *ctr = 0;
    int i = blockIdx.x * 256 + threadIdx.x;
    int j = i & 1023;
    float v = bias[j];
#pragma unroll
    for (int z = 0; z < 8; ++z) v += pco[(size_t)z * 65536 + i];
    co_bf[i] = (ushort)f2bf(tanhf(v));
}

// ---------------------------------------------------------------------------
// Softmax normalize over VOCAB using precomputed gm/ginv
// ---------------------------------------------------------------------------
__global__ __launch_bounds__(256) void softmax_v_k(
    const float* __restrict__ logits, const float* __restrict__ gm,
    const float* __restrict__ ginv, float* __restrict__ out)
{
    int b = blockIdx.y;
    float m = gm[b], inv = ginv[b];
    int v = blockIdx.x * 1024 + threadIdx.x * 4;
    if (v + 3 < VOCAB) {
        float4 lv = *reinterpret_cast<const float4*>(logits + (size_t)b * LOGITS_LD + v);
        float4 o;
        o.x = expf(lv.x - m) * inv; o.y = expf(lv.y - m) * inv;
        o.z = expf(lv.z - m) * inv; o.w = expf(lv.w - m) * inv;
        *reinterpret_cast<float4*>(out + (size_t)b * VOCAB + v) = o;
    } else {
        for (int k = 0; k < 4 && v + k < VOCAB; ++k)
            out[(size_t)b * VOCAB + v + k] = expf(logits[(size_t)b * LOGITS_LD + v + k] - m) * inv;
    }
}

// ---------------------------------------------------------------------------
extern "C" void kernel_launch(void* const* d_in, const int* in_sizes, int n_in,
                              void* d_out, int out_size, void* d_ws, size_t ws_size,
                              hipStream_t stream)
{
    const int*   input_step  = (const int*)  d_in[0];
    const float* last_hidden = (const float*)d_in[1];
    const float* enc         = (const float*)d_in[2];
    const float* emb         = (const float*)d_in[3];
    const float* w_ih0       = (const float*)d_in[4];
    const float* w_hh0       = (const float*)d_in[5];
    const float* b_ih0       = (const float*)d_in[6];
    const float* b_hh0       = (const float*)d_in[7];
    const float* w_ih1       = (const float*)d_in[8];
    const float* w_hh1       = (const float*)d_in[9];
    const float* b_ih1       = (const float*)d_in[10];
    const float* b_hh1       = (const float*)d_in[11];
    const float* concat_w    = (const float*)d_in[12];
    const float* concat_b    = (const float*)d_in[13];
    const float* out_w       = (const float*)d_in[14];
    const float* out_b       = (const float*)d_in[15];

    float* out = (float*)d_out;
    float* out_probs  = out;
    float* out_hidden = out + (size_t)BATCH * VOCAB;

    float* ws   = (float*)d_ws;
    float* big  = ws;                               // aliased region
    float* pgi0 = big;
    float* pgh0 = big + 786432;
    float* pgh1 = big + 1572864;
    float* pgi1 = big;                              // alias
    float* pctx = big;                              // alias
    float* pco  = big;                              // alias
    float* logits = ws + 2359296;                   // 64*LOGITS_LD = 3219456
    float* ci   = logits + (size_t)64 * LOGITS_LD;  // 131072
    float* h0   = ci + 131072;                      // 65536
    float* pm   = h0 + 65536;                       // 2048
    float* ps   = pm + 2048;                        // 2048
    float* pmax = ps + 2048;                        // NSLAB*64 = 50304
    float* psum = pmax + 50304;                     // 50304
    float* gm   = psum + 50304;                     // 64
    float* ginv = gm + 64;                          // 64
    int*   ctr  = (int*)(ginv + 64);                // 16 floats reserved
    ushort* co_bf = (ushort*)(ginv + 64 + 16);      // 65536 ushorts

    Prob P0 = { emb,         input_step, w_ih0, nullptr, pgi0, 3 * HID, EMB, 3 * HID };
    Prob P1 = { last_hidden, nullptr,    w_hh0, nullptr, pgh0, 3 * HID, HID, 3 * HID };
    Prob P2 = { last_hidden + 64 * HID, nullptr, w_hh1, nullptr, pgh1, 3 * HID, HID, 3 * HID };

    // 1. triple GEMM: gi0 (emb-gather), gh0, gh1 — independent. split-K 4.
    gemm_k<256, 0, 0><<<dim3(96, 3, 4), 128, 0, stream>>>(P0, P1, P2);

    // 2. gate layer 0 -> h0 (fp32), out_hidden[0]
    gru_gate_k<4, 4><<<256, 256, 0, stream>>>(pgi0, pgh0, b_ih0, b_hh0, last_hidden,
                                              out_hidden, h0, nullptr);

    // 3. gi1 = h0 @ w_ih1, split-K 8
    Prob PB = { h0, nullptr, w_ih1, nullptr, pgi1, 3 * HID, HID, 3 * HID };
    gemm_k<128, 0, 0><<<dim3(96, 1, 8), 128, 0, stream>>>(PB, PB, PB);

    // 4. gate layer 1 -> out_hidden[1], ci[:, :1024]
    gru_gate_k<8, 4><<<256, 256, 0, stream>>>(pgi1, pgh1, b_ih1, b_hh1,
                                              last_hidden + 64 * HID,
                                              out_hidden + 64 * HID, nullptr, ci);

    // 5. attention: single-pass flash over 32 chunks of 16, then combine
    attn_fused_k<<<dim3(NCHUNK, BATCH), 256, 0, stream>>>(
        out_hidden + 64 * HID, enc, pctx, pm, ps);
    attn_comb_k<<<BATCH, 256, 0, stream>>>(pctx, pm, ps, ci);

    // 6. concat projection: split-K 8 + tanh combine -> co_bf (bf16) + ctr init
    Prob PC = { ci, nullptr, concat_w, nullptr, pco, HID, 2 * HID, HID };
    gemm_k<256, 0, 0><<<dim3(32, 1, 8), 128, 0, stream>>>(PC, PC, PC);
    concat_comb_k<<<256, 256, 0, stream>>>(pco, concat_b, co_bf, ctr);

    // 7. persistent panel-contiguous logits GEMM + fused slab stats
    logits_panel_k<<<512, 256, 0, stream>>>(co_bf, out_w, out_b, logits, pmax, psum, ctr);

    // 8. stats combine + softmax normalize
    vfinal_k<<<BATCH, 256, 0, stream>>>(pmax, psum, gm, ginv);
    softmax_v_k<<<dim3((VOCAB + 1023) / 1024, BATCH), 256, 0, stream>>>(
        logits, gm, ginv, out_probs);
}